// Round 1
// baseline (365.062 us; speedup 1.0000x reference)
//
#include <hip/hip_runtime.h>
#include <hip/hip_bf16.h>

#define B_DIM 32
#define T_DIM 2048
#define D_DIM 1024
#define S_MAXK 32

constexpr int NSLICE = 16;            // d-slices per b
constexpr int SLICE  = D_DIM / NSLICE; // 64 floats per slice

// ws layout (bytes):
//   sums   float[B][32][D]   @ 0        : 4,194,304
//   counts uint [B][32]      @ 4194304  : 4,096
//   res    float[B][2]       @ 4198400  : 256
//   pos    uint [B][32]      @ 4198656  : 4,096   (memset 0xFF)
#define SUMS_OFF   0
#define COUNTS_OFF 4194304
#define RES_OFF    4198400
#define POS_OFF    4198656

__global__ __launch_bounds__(256) void k_accum(const float* __restrict__ x,
                                               const int* __restrict__ sid,
                                               float* __restrict__ sums,
                                               unsigned* __restrict__ counts,
                                               unsigned* __restrict__ pos) {
    __shared__ float acc[S_MAXK * SLICE];   // 32*64*4B = 8 KB
    const int b  = blockIdx.x / NSLICE;
    const int ds = blockIdx.x % NSLICE;
    const int dbase = ds * SLICE;
    const int tid = threadIdx.x;

    for (int i = tid; i < S_MAXK * SLICE; i += 256) acc[i] = 0.0f;

    if (ds == 0) {
        // counts / first-occurrence positions (one slice does it)
        for (int t = tid; t < T_DIM; t += 256) {
            int s = sid[b * T_DIM + t];
            if ((unsigned)(s - 1) < 32u) {
                atomicAdd(&counts[b * 32 + (s - 1)], 1u);
                atomicMin(&pos[b * 32 + (s - 1)], (unsigned)t);
            }
        }
    }
    __syncthreads();

    const int laned = tid & (SLICE / 4 - 1);  // 16 lanes of float4 -> 64 d
    const int trow  = tid >> 4;               // 16 t-rows in flight
    const float4* xp = (const float4*)x;
    const size_t row_stride = D_DIM / 4;

    #pragma unroll 4
    for (int t = trow; t < T_DIM; t += 16) {
        int s = sid[b * T_DIM + t];
        float4 v = xp[(size_t)(b * T_DIM + t) * row_stride + (dbase / 4) + laned];
        if ((unsigned)(s - 1) < 32u) {
            float* a = &acc[(s - 1) * SLICE + laned * 4];
            atomicAdd(a + 0, fabsf(v.x));
            atomicAdd(a + 1, fabsf(v.y));
            atomicAdd(a + 2, fabsf(v.z));
            atomicAdd(a + 3, fabsf(v.w));
        }
    }
    __syncthreads();

    // flush: each (b,s,d) owned by exactly this block -> plain stores
    for (int i = tid; i < S_MAXK * SLICE; i += 256) {
        int s  = i / SLICE;
        int dd = i % SLICE;
        sums[((size_t)b * 32 + s) * D_DIM + dbase + dd] = acc[i];
    }
}

__global__ __launch_bounds__(256) void k_pairs(const float* __restrict__ sums,
                                               const unsigned* __restrict__ counts,
                                               const unsigned* __restrict__ pos,
                                               const int* __restrict__ labels,
                                               float* __restrict__ res) {
    const int b = blockIdx.x;
    const int tid = threadIdx.x;
    __shared__ unsigned posl[32];
    __shared__ float    rcp[32];
    __shared__ int      ordl[32];
    __shared__ float    El[31];

    if (tid < 32) {
        unsigned p = pos[b * 32 + tid];
        posl[tid] = p;
        unsigned c = counts[b * 32 + tid];
        rcp[tid] = 1.0f / (float)(c > 1u ? c : 1u);
    }
    __syncthreads();
    if (tid < 32) {
        unsigned ps = posl[tid];
        int r = 0;
        for (int j = 0; j < 32; ++j) {
            unsigned pj = posl[j];
            if (pj < ps || (pj == ps && j < tid)) r++;
        }
        ordl[r] = tid;   // stable argsort of pos
    }
    __syncthreads();

    const int wave = tid >> 6;
    const int lane = tid & 63;
    for (int i = wave; i < 31; i += 4) {
        int A  = ordl[i];
        int B2 = ordl[i + 1];
        const float* pa = &sums[((size_t)b * 32 + A)  * D_DIM];
        const float* pb = &sums[((size_t)b * 32 + B2) * D_DIM];
        float ra = rcp[A], rb = rcp[B2];
        float ssum = 0.0f;
        for (int d = lane * 4; d < D_DIM; d += 256) {
            float4 a4 = *(const float4*)(pa + d);
            float4 b4 = *(const float4*)(pb + d);
            float d0 = fmaxf(a4.x * ra - b4.x * rb, 0.0f);
            float d1 = fmaxf(a4.y * ra - b4.y * rb, 0.0f);
            float d2 = fmaxf(a4.z * ra - b4.z * rb, 0.0f);
            float d3 = fmaxf(a4.w * ra - b4.w * rb, 0.0f);
            ssum += d0 * d0 + d1 * d1 + d2 * d2 + d3 * d3;
        }
        #pragma unroll
        for (int off = 32; off; off >>= 1) ssum += __shfl_down(ssum, off);
        if (lane == 0) El[i] = ssum * (1.0f / D_DIM);
    }
    __syncthreads();

    if (tid == 0) {
        float lpos = 0.0f, lneg = 0.0f;
        int np = 0, ni = 0, n = 0;
        for (int s2 = 0; s2 < 32; ++s2) n += (posl[s2] < T_DIM) ? 1 : 0;
        for (int i = 0; i < 31; ++i) {
            int A  = ordl[i];
            int B2 = ordl[i + 1];
            if (posl[B2] < T_DIM) {         // pair_valid
                float E = El[i];
                np++; lpos += E;
                if (A > B2) {               // inversion in step order
                    ni++; lneg += fmaxf(1.0f - E, 0.0f);   // ALPHA = 1
                }
            }
        }
        float loss_pos = lpos / (float)(np > 1 ? np : 1);
        float loss_neg = lneg / (float)(ni > 1 ? ni : 1);
        int lab = labels[b];
        bool pc = (lab == 1) && (n >= 2);
        bool nc = (lab == 0) && (ni > 0);
        res[b * 2 + 0] = (pc ? loss_pos : 0.0f) + (nc ? loss_neg : 0.0f);
        res[b * 2 + 1] = (float)((pc ? 1 : 0) + (nc ? 1 : 0));
    }
}

__global__ void k_final(const float* __restrict__ res, float* __restrict__ out) {
    const int lane = threadIdx.x;
    float t = 0.0f, c = 0.0f;
    if (lane < 32) { t = res[lane * 2]; c = res[lane * 2 + 1]; }
    #pragma unroll
    for (int off = 32; off; off >>= 1) {
        t += __shfl_down(t, off);
        c += __shfl_down(c, off);
    }
    if (lane == 0) out[0] = t / (c + 1e-9f);
}

extern "C" void kernel_launch(void* const* d_in, const int* in_sizes, int n_in,
                              void* d_out, int out_size, void* d_ws, size_t ws_size,
                              hipStream_t stream) {
    const float* x      = (const float*)d_in[0];
    const int*   sid    = (const int*)d_in[1];
    const int*   labels = (const int*)d_in[2];
    float* out = (float*)d_out;
    char*  ws  = (char*)d_ws;

    float*    sums   = (float*)(ws + SUMS_OFF);
    unsigned* counts = (unsigned*)(ws + COUNTS_OFF);
    float*    res    = (float*)(ws + RES_OFF);
    unsigned* pos    = (unsigned*)(ws + POS_OFF);

    hipMemsetAsync(ws, 0, RES_OFF, stream);                 // sums + counts
    hipMemsetAsync(ws + POS_OFF, 0xFF, 4096, stream);       // pos sentinel

    k_accum<<<B_DIM * NSLICE, 256, 0, stream>>>(x, sid, sums, counts, pos);
    k_pairs<<<B_DIM, 256, 0, stream>>>(sums, counts, pos, labels, res);
    k_final<<<1, 64, 0, stream>>>(res, out);
}

// Round 2
// 69.841 us; speedup vs baseline: 5.2270x; 5.2270x over previous
//
#include <hip/hip_runtime.h>
#include <hip/hip_bf16.h>

#define B_DIM 32
#define T_DIM 2048
#define D_DIM 1024
#define S_MAXK 32

// ws layout (bytes):
//   h      float[B][32][D]   @ 0        : 4,194,304   (already divided by count)
//   counts uint [B][32]      @ 4194304  : 4,096
//   res    float[B][2]       @ 4198400  : 256
//   pos    uint [B][32]      @ 4198656  : 4,096
#define H_OFF      0
#define COUNTS_OFF 4194304
#define RES_OFF    4198400
#define POS_OFF    4198656

// One block per (b, step). Scan sid row -> match list in LDS (no global
// atomics), then register-accumulate |x| over matching rows, 4-deep batched
// loads for memory-level parallelism. Each x row is read by exactly one block.
__global__ __launch_bounds__(256) void k_gather(const float* __restrict__ x,
                                                const int* __restrict__ sid,
                                                float* __restrict__ h,
                                                unsigned* __restrict__ counts,
                                                unsigned* __restrict__ pos) {
    __shared__ int      list[T_DIM];
    __shared__ int      cnt;
    __shared__ unsigned firstpos;

    const int b = blockIdx.x >> 5;        // blocks with same b adjacent (sid L2 reuse)
    const int s = blockIdx.x & 31;        // step value = s+1
    const int tid = threadIdx.x;

    if (tid == 0) { cnt = 0; firstpos = 0xFFFFFFFFu; }
    __syncthreads();

    const int* srow = sid + b * T_DIM;
    unsigned myfirst = 0xFFFFFFFFu;
    for (int t = tid; t < T_DIM; t += 256) {
        if (srow[t] == s + 1) {
            int idx = atomicAdd(&cnt, 1);   // LDS atomic, tiny traffic
            list[idx] = t;
            if ((unsigned)t < myfirst) myfirst = (unsigned)t;
        }
    }
    if (myfirst != 0xFFFFFFFFu) atomicMin(&firstpos, myfirst);
    __syncthreads();

    const int n = cnt;
    const float4* xb = (const float4*)(x + (size_t)b * T_DIM * D_DIM);
    const int dcol = tid;                  // float4 column: d = tid*4
    float4 acc = {0.f, 0.f, 0.f, 0.f};

    int i = 0;
    for (; i + 4 <= n; i += 4) {
        int t0 = list[i], t1 = list[i + 1], t2 = list[i + 2], t3 = list[i + 3];
        float4 v0 = xb[(size_t)t0 * (D_DIM / 4) + dcol];
        float4 v1 = xb[(size_t)t1 * (D_DIM / 4) + dcol];
        float4 v2 = xb[(size_t)t2 * (D_DIM / 4) + dcol];
        float4 v3 = xb[(size_t)t3 * (D_DIM / 4) + dcol];
        acc.x += fabsf(v0.x) + fabsf(v1.x) + fabsf(v2.x) + fabsf(v3.x);
        acc.y += fabsf(v0.y) + fabsf(v1.y) + fabsf(v2.y) + fabsf(v3.y);
        acc.z += fabsf(v0.z) + fabsf(v1.z) + fabsf(v2.z) + fabsf(v3.z);
        acc.w += fabsf(v0.w) + fabsf(v1.w) + fabsf(v2.w) + fabsf(v3.w);
    }
    for (; i < n; ++i) {
        float4 v = xb[(size_t)list[i] * (D_DIM / 4) + dcol];
        acc.x += fabsf(v.x); acc.y += fabsf(v.y);
        acc.z += fabsf(v.z); acc.w += fabsf(v.w);
    }

    const float r = 1.0f / (float)(n > 1 ? n : 1);
    float4 out4 = {acc.x * r, acc.y * r, acc.z * r, acc.w * r};
    ((float4*)(h + ((size_t)b * 32 + s) * D_DIM))[dcol] = out4;

    if (tid == 0) {
        counts[b * 32 + s] = (unsigned)n;
        pos[b * 32 + s] = (n > 0) ? firstpos : (unsigned)T_DIM;
    }
}

__global__ __launch_bounds__(256) void k_pairs(const float* __restrict__ h,
                                               const unsigned* __restrict__ counts,
                                               const unsigned* __restrict__ pos,
                                               const int* __restrict__ labels,
                                               float* __restrict__ res) {
    const int b = blockIdx.x;
    const int tid = threadIdx.x;
    __shared__ unsigned posl[32];
    __shared__ int      ordl[32];
    __shared__ float    El[31];

    if (tid < 32) posl[tid] = pos[b * 32 + tid];
    __syncthreads();
    if (tid < 32) {
        unsigned ps = posl[tid];
        int r = 0;
        for (int j = 0; j < 32; ++j) {
            unsigned pj = posl[j];
            if (pj < ps || (pj == ps && j < tid)) r++;
        }
        ordl[r] = tid;   // stable argsort of pos
    }
    __syncthreads();

    const int wave = tid >> 6;
    const int lane = tid & 63;
    for (int i = wave; i < 31; i += 4) {
        int A  = ordl[i];
        int B2 = ordl[i + 1];
        const float* pa = &h[((size_t)b * 32 + A)  * D_DIM];
        const float* pb = &h[((size_t)b * 32 + B2) * D_DIM];
        float ssum = 0.0f;
        for (int d = lane * 4; d < D_DIM; d += 256) {
            float4 a4 = *(const float4*)(pa + d);
            float4 b4 = *(const float4*)(pb + d);
            float d0 = fmaxf(a4.x - b4.x, 0.0f);
            float d1 = fmaxf(a4.y - b4.y, 0.0f);
            float d2 = fmaxf(a4.z - b4.z, 0.0f);
            float d3 = fmaxf(a4.w - b4.w, 0.0f);
            ssum += d0 * d0 + d1 * d1 + d2 * d2 + d3 * d3;
        }
        #pragma unroll
        for (int off = 32; off; off >>= 1) ssum += __shfl_down(ssum, off);
        if (lane == 0) El[i] = ssum * (1.0f / D_DIM);
    }
    __syncthreads();

    if (tid == 0) {
        float lpos = 0.0f, lneg = 0.0f;
        int np = 0, ni = 0, n = 0;
        for (int s2 = 0; s2 < 32; ++s2) n += (posl[s2] < T_DIM) ? 1 : 0;
        for (int i = 0; i < 31; ++i) {
            int A  = ordl[i];
            int B2 = ordl[i + 1];
            if (posl[B2] < T_DIM) {         // pair_valid
                float E = El[i];
                np++; lpos += E;
                if (A > B2) {               // inversion in step order
                    ni++; lneg += fmaxf(1.0f - E, 0.0f);   // ALPHA = 1
                }
            }
        }
        float loss_pos = lpos / (float)(np > 1 ? np : 1);
        float loss_neg = lneg / (float)(ni > 1 ? ni : 1);
        int lab = labels[b];
        bool pc = (lab == 1) && (n >= 2);
        bool nc = (lab == 0) && (ni > 0);
        res[b * 2 + 0] = (pc ? loss_pos : 0.0f) + (nc ? loss_neg : 0.0f);
        res[b * 2 + 1] = (float)((pc ? 1 : 0) + (nc ? 1 : 0));
    }
}

__global__ void k_final(const float* __restrict__ res, float* __restrict__ out) {
    const int lane = threadIdx.x;
    float t = 0.0f, c = 0.0f;
    if (lane < 32) { t = res[lane * 2]; c = res[lane * 2 + 1]; }
    #pragma unroll
    for (int off = 32; off; off >>= 1) {
        t += __shfl_down(t, off);
        c += __shfl_down(c, off);
    }
    if (lane == 0) out[0] = t / (c + 1e-9f);
}

extern "C" void kernel_launch(void* const* d_in, const int* in_sizes, int n_in,
                              void* d_out, int out_size, void* d_ws, size_t ws_size,
                              hipStream_t stream) {
    const float* x      = (const float*)d_in[0];
    const int*   sid    = (const int*)d_in[1];
    const int*   labels = (const int*)d_in[2];
    float* out = (float*)d_out;
    char*  ws  = (char*)d_ws;

    float*    h      = (float*)(ws + H_OFF);
    unsigned* counts = (unsigned*)(ws + COUNTS_OFF);
    float*    res    = (float*)(ws + RES_OFF);
    unsigned* pos    = (unsigned*)(ws + POS_OFF);

    k_gather<<<B_DIM * S_MAXK, 256, 0, stream>>>(x, sid, h, counts, pos);
    k_pairs<<<B_DIM, 256, 0, stream>>>(h, counts, pos, labels, res);
    k_final<<<1, 64, 0, stream>>>(res, out);
}